// Round 8
// baseline (97.413 us; speedup 1.0000x reference)
//
#include <hip/hip_runtime.h>
#include <math.h>

// DGP loss — ROUND 8: single fused kernel (no fin node) + fma screen.
// Semantics locked (bit-exact R5-R7, absmax 0.0): bf16-RNE-round input reads,
// np fp32 chain (IEEE div/sqrt, numpy 8-acc pairwise channel sum with
// contract(off) so t*t rounds separately), CR fp32 expm1 via fp64, cnt==2,
// double accumulate, /3534400.
//
// R7 post-mortem: graded dur has ~75us harness floor (256MiB ws poison fill =
// 43us @ 80% HBM peak + restores + sync); controllable slice = graph nodes
// (~3-4us each) + ~6us kernel. This round: remove the fin node via the
// "last block" ticket idiom (ticket lives in poisoned d_ws: accept BOTH
// init=0xAAAAAAAA (timed: harness poisons ws to 0xAA) and init=0
// (correctness call / fresh alloc) — ranges can't collide), and screen taps
// with an fma-based sq (error <= 4e-5 at sq~18, margin 1e-3; exact numpy
// chain only for sq_fast <= 18.001, P ~ 3e-5/tap, so the contract-off chain
// + masks + expm1 are cold).

#define HP    188
#define IMW   192
#define NCH   32
#define TW    64
#define HWC   68          // 64 + 4 halo cols
#define NR    5           // 1 output row + 4 halo rows
#define PLANE (IMW * IMW)
#define NBLK  (3 * HP * 2)   // 1128 blocks

__device__ __forceinline__ float bf16_rne(float f) {
    unsigned u = __float_as_uint(f);
    u += 0x7fffu + ((u >> 16) & 1u);   // round-to-nearest-even to bf16 grid
    u &= 0xffff0000u;
    return __uint_as_float(u);
}

__global__ __launch_bounds__(256) void dgp_fused(
    const float* __restrict__ S,   // [2,32,192,192] bf16-grid values in f32
    const float* __restrict__ D,   // [2,1,192,192]
    unsigned long long* __restrict__ partials,  // [NBLK] double bits, atomics
    unsigned int* __restrict__ ticket,          // 1 word, poison/zero init
    float* __restrict__ out)
{
    __shared__ __align__(16) float sm[8][NR][HWC][4];  // 43520 B quad-interleave
    __shared__ float  rd[NR][HWC];
    __shared__ double wsum[4];
    __shared__ int    slast;

    const int tid = threadIdx.x;
    const int tx  = tid & 63;        // position within row-tile
    const int tg  = tid >> 6;        // tap group (wave-uniform)
    const int ox0 = blockIdx.x * TW;
    const int oy  = blockIdx.y;      // patch row (0..187)
    const int b   = blockIdx.z;

    // ---- stage reciprocal depth (bf16_rne then IEEE f32 div) ----
    for (int t = tid; t < NR * HWC; t += 256) {
        const int i   = t / HWC;
        const int col = t - i * HWC;
        const int gc  = ox0 + col;
        const float d = (gc < IMW) ? bf16_rne(D[(b * IMW + (oy + i)) * IMW + gc])
                                   : 1.0f;
        rd[i][col] = 1.0f / (d + 1e-6f);
    }

    // ---- stage semantics: one float4 = 4 channels of one pixel ----
    for (int t = tid; t < 8 * NR * HWC; t += 256) {
        const int q   = t / (NR * HWC);
        const int rem = t - q * (NR * HWC);
        const int i   = rem / HWC;
        const int col = rem - i * HWC;
        const int gc  = ox0 + col;
        float4 v = make_float4(0.f, 0.f, 0.f, 0.f);
        if (gc < IMW) {
            const int base = ((b * NCH + 4 * q) * IMW + (oy + i)) * IMW + gc;
            v.x = bf16_rne(S[base]);
            v.y = bf16_rne(S[base + PLANE]);
            v.z = bf16_rne(S[base + 2 * PLANE]);
            v.w = bf16_rne(S[base + 3 * PLANE]);
        }
        *(float4*)&sm[q][i][col][0] = v;
    }
    __syncthreads();

    double acc = 0.0;
    const int ox = ox0 + tx;
    if (ox < HP) {
        float cs[NCH];
#pragma unroll
        for (int q = 0; q < 8; ++q) {
            const float4 c4 = *(const float4*)&sm[q][2][tx + 2][0];
            cs[4 * q + 0] = c4.x;
            cs[4 * q + 1] = c4.y;
            cs[4 * q + 2] = c4.z;
            cs[4 * q + 3] = c4.w;
        }
        const float rc = rd[2][tx + 2];

        for (int k = 0; k < 6; ++k) {
            int t = tg * 6 + k;
            t += (t >= 12);                 // skip center tap (i=2,j=2)
            const int i = t / 5;
            const int j = t - 5 * i;

            // ---- HOT: fma screen (any rounding; conservative by 25x) ----
            float f0 = 0.f, f1 = 0.f, f2 = 0.f, f3 = 0.f;
#pragma unroll
            for (int q = 0; q < 8; ++q) {
                const float4 x = *(const float4*)&sm[q][i][tx + j][0];
                const float t0 = cs[4 * q + 0] - x.x;
                const float t1 = cs[4 * q + 1] - x.y;
                const float t2 = cs[4 * q + 2] - x.z;
                const float t3 = cs[4 * q + 3] - x.w;
                f0 = fmaf(t0, t0, f0);
                f1 = fmaf(t1, t1, f1);
                f2 = fmaf(t2, t2, f2);
                f3 = fmaf(t3, t3, f3);
            }
            const float sq_fast = (f0 + f1) + (f2 + f3);

            if (sq_fast <= 18.001f) {
                // ---- COLD (P~3e-5/tap): exact numpy chain, verbatim R7 ----
                const float rn = rd[i][tx + j];
                const float dd = fabsf(rc - rn);

                float r[8];
                {
#pragma clang fp contract(off)
#pragma unroll
                    for (int blk = 0; blk < 4; ++blk) {
                        const float4 e = *(const float4*)&sm[2 * blk][i][tx + j][0];
                        const float4 o = *(const float4*)&sm[2 * blk + 1][i][tx + j][0];
                        float p;
                        p = cs[8 * blk + 0] - e.x; p = p * p; r[0] = blk ? r[0] + p : p;
                        p = cs[8 * blk + 1] - e.y; p = p * p; r[1] = blk ? r[1] + p : p;
                        p = cs[8 * blk + 2] - e.z; p = p * p; r[2] = blk ? r[2] + p : p;
                        p = cs[8 * blk + 3] - e.w; p = p * p; r[3] = blk ? r[3] + p : p;
                        p = cs[8 * blk + 4] - o.x; p = p * p; r[4] = blk ? r[4] + p : p;
                        p = cs[8 * blk + 5] - o.y; p = p * p; r[5] = blk ? r[5] + p : p;
                        p = cs[8 * blk + 6] - o.z; p = p * p; r[6] = blk ? r[6] + p : p;
                        p = cs[8 * blk + 7] - o.w; p = p * p; r[7] = blk ? r[7] + p : p;
                    }
                }
                const float sq = ((r[0] + r[1]) + (r[2] + r[3]))
                               + ((r[4] + r[5]) + (r[6] + r[7]));

                const float sd  = sqrtf(sq);            // IEEE f32 sqrt
                const float ddc = fmaxf(dd, 1e-8f);
                const float sdc = fmaxf(sd, 1e-8f);

                if (ddc > 1e-8f && sdc > 1e-8f) {
                    const float s2 = sdc * sdc;
                    if (s2 <= 18.0f) {                  // else l_sem == 0 exactly
                        const float ls = (float)expm1(-(double)s2) + 1.0f;
                        const float ad = -(ddc / 10.0f);
                        const float ld = (float)expm1((double)ad) + 1.0f;
                        acc += 2.0 * (double)(ld * ls); // cnt == 2
                    }
                }
            }
        }
    }

    // ---- block reduce (double) ----
#pragma unroll
    for (int off = 32; off > 0; off >>= 1)
        acc += __shfl_down(acc, off);
    if ((tid & 63) == 0) wsum[tid >> 6] = acc;
    __syncthreads();

    // ---- publish partial + ticket; last block finalizes ----
    const int blk = (blockIdx.z * gridDim.y + blockIdx.y) * gridDim.x
                  + blockIdx.x;
    if (tid == 0) {
        const double v = wsum[0] + wsum[1] + wsum[2] + wsum[3];
        unsigned long long bits;
        __builtin_memcpy(&bits, &v, 8);
        atomicExch(&partials[blk], bits);     // device-scope, L2-coherent
        __threadfence();
        const unsigned int old = atomicAdd(ticket, 1u);
        // last block iff old == init + NBLK-1; init is 0xAAAAAAAA (timed:
        // harness poisons ws to 0xAA) or 0 (correctness/fresh). Ranges of
        // observable olds for the two inits cannot collide.
        slast = (old == (unsigned)(NBLK - 1)) ||
                (old == 0xAAAAAAAAu + (unsigned)(NBLK - 1));
    }
    __syncthreads();

    if (slast) {
        __threadfence();
        double tot = 0.0;
        for (int kk = tid; kk < NBLK; kk += 256) {
            const unsigned long long bits = atomicAdd(&partials[kk], 0ull);
            double v;
            __builtin_memcpy(&v, &bits, 8);
            tot += v;
        }
#pragma unroll
        for (int off = 32; off > 0; off >>= 1)
            tot += __shfl_down(tot, off);
        if ((tid & 63) == 0) wsum[tid >> 6] = tot;
        __syncthreads();
        if (tid == 0)
            out[0] = (float)((wsum[0] + wsum[1] + wsum[2] + wsum[3]) / 3534400.0);
    }
}

extern "C" void kernel_launch(void* const* d_in, const int* in_sizes, int n_in,
                              void* d_out, int out_size, void* d_ws, size_t ws_size,
                              hipStream_t stream)
{
    // semantic = 2359296 elems, depth = 73728 elems (bind by size for safety)
    const float* S = (const float*)d_in[0];
    const float* D = (const float*)d_in[1];
    if (n_in >= 2 && in_sizes[0] < in_sizes[1]) {
        S = (const float*)d_in[1];
        D = (const float*)d_in[0];
    }
    unsigned long long* partials = (unsigned long long*)d_ws;          // 1128*8 B
    unsigned int*       ticket   = (unsigned int*)((char*)d_ws + 16 * 1024);

    dim3 grid(3, HP, 2);   // 1128 blocks
    dgp_fused<<<grid, 256, 0, stream>>>(S, D, partials, ticket, (float*)d_out);
}

// Round 9
// 76.744 us; speedup vs baseline: 1.2693x; 1.2693x over previous
//
#include <hip/hip_runtime.h>
#include <math.h>

// DGP loss — ROUND 9: revert R8's fused ticket/fence design (device-scope
// __threadfence per block = per-XCD L2 writeback on CDNA4 -> nuked locality,
// +13us). Back to 2 kernels (plain partial stores; kernel boundary is the
// coherence point). NEW: staging with full memory-level parallelism — issue
// ALL ~44 global loads per thread into registers (phase 1), then rne +
// ds_write (phase 2). R8's counters showed the old load->rne->write loop
// serialized at vmcnt(0) per iteration (4 loads in flight, ~11 cold-HBM
// round-trips/block => 31-44us kernel at 625 GB/s / 16% VALU).
//
// Semantics locked (bit-exact R5-R8, absmax 0.0): bf16-RNE-round input reads,
// np fp32 chain (IEEE div/sqrt, numpy 8-acc pairwise channel sum with
// contract(off)), CR fp32 expm1 via fp64, cnt==2, double accumulate, /3534400.
// fma screen (error <=7e-5 at sq~18 vs 1e-3 margin) keeps the exact chain cold.

#define HP    188
#define IMW   192
#define NCH   32
#define TW    64
#define HWC   68          // 64 + 4 halo cols
#define NR    5           // 1 output row + 4 halo rows
#define PLANE (IMW * IMW)
#define NBLK  (3 * HP * 2)   // 1128 blocks
#define NSLOT (8 * NR * HWC) // 2720 float4 staging slots
#define SPT   11             // ceil(2720/256) slots per thread

__device__ __forceinline__ float bf16_rne(float f) {
    unsigned u = __float_as_uint(f);
    u += 0x7fffu + ((u >> 16) & 1u);   // round-to-nearest-even to bf16 grid
    u &= 0xffff0000u;
    return __uint_as_float(u);
}

__global__ __launch_bounds__(256) void dgp_tiled(
    const float* __restrict__ S,   // [2,32,192,192] bf16-grid values in f32
    const float* __restrict__ D,   // [2,1,192,192]
    double* __restrict__ partials) // [NBLK] plain stores
{
    __shared__ __align__(16) float sm[8][NR][HWC][4];  // 43520 B quad-interleave
    __shared__ float  rd[NR][HWC];
    __shared__ double wsum[4];

    const int tid = threadIdx.x;
    const int tx  = tid & 63;
    const int tg  = tid >> 6;
    const int ox0 = blockIdx.x * TW;
    const int oy  = blockIdx.y;      // patch row (0..187)
    const int b   = blockIdx.z;

    // ---------- phase 1: issue ALL staging loads (max MLP) ----------
    // depth: 340 slots -> 2 per thread
    float dv[2];
#pragma unroll
    for (int s = 0; s < 2; ++s) {
        const int t = tid + 256 * s;
        float d = 1.0f;
        if (t < NR * HWC) {
            const int i   = t / HWC;
            const int col = t - i * HWC;
            const int gc  = ox0 + col;
            if (gc < IMW) d = D[(b * IMW + (oy + i)) * IMW + gc];
        }
        dv[s] = d;
    }
    // semantics: 2720 float4 slots -> 11 per thread (4 plane-strided loads each)
    float4 sv[SPT];
#pragma unroll
    for (int s = 0; s < SPT; ++s) {
        const int t = tid + 256 * s;
        float4 v = make_float4(0.f, 0.f, 0.f, 0.f);
        if (t < NSLOT) {
            const int q   = t / (NR * HWC);
            const int rem = t - q * (NR * HWC);
            const int i   = rem / HWC;
            const int col = rem - i * HWC;
            const int gc  = ox0 + col;
            if (gc < IMW) {
                const int base = ((b * NCH + 4 * q) * IMW + (oy + i)) * IMW + gc;
                v.x = S[base];
                v.y = S[base + PLANE];
                v.z = S[base + 2 * PLANE];
                v.w = S[base + 3 * PLANE];
            }
        }
        sv[s] = v;
    }

    // ---------- phase 2: convert + LDS write (loads drain in order) ----------
#pragma unroll
    for (int s = 0; s < 2; ++s) {
        const int t = tid + 256 * s;
        if (t < NR * HWC) {
            const int i   = t / HWC;
            const int col = t - i * HWC;
            rd[i][col] = 1.0f / (bf16_rne(dv[s]) + 1e-6f);
        }
    }
#pragma unroll
    for (int s = 0; s < SPT; ++s) {
        const int t = tid + 256 * s;
        if (t < NSLOT) {
            const int q   = t / (NR * HWC);
            const int rem = t - q * (NR * HWC);
            const int i   = rem / HWC;
            const int col = rem - i * HWC;
            float4 v = sv[s];
            v.x = bf16_rne(v.x);
            v.y = bf16_rne(v.y);
            v.z = bf16_rne(v.z);
            v.w = bf16_rne(v.w);
            *(float4*)&sm[q][i][col][0] = v;
        }
    }
    __syncthreads();

    // ---------- compute: 64 positions x 4 tap-groups (6 taps each) ----------
    double acc = 0.0;
    const int ox = ox0 + tx;
    if (ox < HP) {
        float cs[NCH];
#pragma unroll
        for (int q = 0; q < 8; ++q) {
            const float4 c4 = *(const float4*)&sm[q][2][tx + 2][0];
            cs[4 * q + 0] = c4.x;
            cs[4 * q + 1] = c4.y;
            cs[4 * q + 2] = c4.z;
            cs[4 * q + 3] = c4.w;
        }
        const float rc = rd[2][tx + 2];

        for (int k = 0; k < 6; ++k) {
            int t = tg * 6 + k;
            t += (t >= 12);                 // skip center tap (i=2,j=2)
            const int i = t / 5;
            const int j = t - 5 * i;

            // HOT: fma screen (conservative; abs err <=7e-5 vs 1e-3 margin)
            float f0 = 0.f, f1 = 0.f, f2 = 0.f, f3 = 0.f;
#pragma unroll
            for (int q = 0; q < 8; ++q) {
                const float4 x = *(const float4*)&sm[q][i][tx + j][0];
                const float t0 = cs[4 * q + 0] - x.x;
                const float t1 = cs[4 * q + 1] - x.y;
                const float t2 = cs[4 * q + 2] - x.z;
                const float t3 = cs[4 * q + 3] - x.w;
                f0 = fmaf(t0, t0, f0);
                f1 = fmaf(t1, t1, f1);
                f2 = fmaf(t2, t2, f2);
                f3 = fmaf(t3, t3, f3);
            }
            const float sq_fast = (f0 + f1) + (f2 + f3);

            if (sq_fast <= 18.001f) {
                // COLD (P~3e-5): exact numpy chain, verbatim R5
                const float rn = rd[i][tx + j];
                const float dd = fabsf(rc - rn);

                float r[8];
                {
#pragma clang fp contract(off)
#pragma unroll
                    for (int blk = 0; blk < 4; ++blk) {
                        const float4 e = *(const float4*)&sm[2 * blk][i][tx + j][0];
                        const float4 o = *(const float4*)&sm[2 * blk + 1][i][tx + j][0];
                        float p;
                        p = cs[8 * blk + 0] - e.x; p = p * p; r[0] = blk ? r[0] + p : p;
                        p = cs[8 * blk + 1] - e.y; p = p * p; r[1] = blk ? r[1] + p : p;
                        p = cs[8 * blk + 2] - e.z; p = p * p; r[2] = blk ? r[2] + p : p;
                        p = cs[8 * blk + 3] - e.w; p = p * p; r[3] = blk ? r[3] + p : p;
                        p = cs[8 * blk + 4] - o.x; p = p * p; r[4] = blk ? r[4] + p : p;
                        p = cs[8 * blk + 5] - o.y; p = p * p; r[5] = blk ? r[5] + p : p;
                        p = cs[8 * blk + 6] - o.z; p = p * p; r[6] = blk ? r[6] + p : p;
                        p = cs[8 * blk + 7] - o.w; p = p * p; r[7] = blk ? r[7] + p : p;
                    }
                }
                const float sq = ((r[0] + r[1]) + (r[2] + r[3]))
                               + ((r[4] + r[5]) + (r[6] + r[7]));

                const float sd  = sqrtf(sq);
                const float ddc = fmaxf(dd, 1e-8f);
                const float sdc = fmaxf(sd, 1e-8f);

                if (ddc > 1e-8f && sdc > 1e-8f) {
                    const float s2 = sdc * sdc;
                    if (s2 <= 18.0f) {                  // else l_sem == 0 exactly
                        const float ls = (float)expm1(-(double)s2) + 1.0f;
                        const float ad = -(ddc / 10.0f);
                        const float ld = (float)expm1((double)ad) + 1.0f;
                        acc += 2.0 * (double)(ld * ls); // cnt == 2
                    }
                }
            }
        }
    }

    // block reduce (double) + ONE plain store per block
#pragma unroll
    for (int off = 32; off > 0; off >>= 1)
        acc += __shfl_down(acc, off);
    if ((tid & 63) == 0) wsum[tid >> 6] = acc;
    __syncthreads();
    if (tid == 0) {
        const int blk = (blockIdx.z * gridDim.y + blockIdx.y) * gridDim.x
                      + blockIdx.x;
        partials[blk] = wsum[0] + wsum[1] + wsum[2] + wsum[3];
    }
}

__global__ __launch_bounds__(256) void dgp_fin(
    const double* __restrict__ partials, float* __restrict__ out)
{
    const int tid = threadIdx.x;
    double acc = 0.0;
    for (int k = tid; k < NBLK; k += 256)
        acc += partials[k];
#pragma unroll
    for (int off = 32; off > 0; off >>= 1)
        acc += __shfl_down(acc, off);
    __shared__ double ws[4];
    if ((tid & 63) == 0) ws[tid >> 6] = acc;
    __syncthreads();
    if (tid == 0)
        out[0] = (float)((ws[0] + ws[1] + ws[2] + ws[3]) / 3534400.0);
}

extern "C" void kernel_launch(void* const* d_in, const int* in_sizes, int n_in,
                              void* d_out, int out_size, void* d_ws, size_t ws_size,
                              hipStream_t stream)
{
    const float* S = (const float*)d_in[0];
    const float* D = (const float*)d_in[1];
    if (n_in >= 2 && in_sizes[0] < in_sizes[1]) {
        S = (const float*)d_in[1];
        D = (const float*)d_in[0];
    }
    double* partials = (double*)d_ws;   // 1128 * 8 B, every slot written

    dim3 grid(3, HP, 2);   // 1128 blocks
    dgp_tiled<<<grid, 256, 0, stream>>>(S, D, partials);
    dgp_fin<<<1, 256, 0, stream>>>(partials, (float*)d_out);
}